// Round 10
// baseline (449.316 us; speedup 1.0000x reference)
//
#include <hip/hip_runtime.h>
#include <hip/hip_bf16.h>
#include <stdint.h>

#define M_DIM 8192   // rows of x / out
#define K_DIM 4096   // inner dim
#define N_DIM 4096   // cols of out = rows of W

typedef int intx4  __attribute__((ext_vector_type(4)));
typedef int intx16 __attribute__((ext_vector_type(16)));

// ---------------------------------------------------------------------------
// FRAGMENT-MAJOR workspace layout (round-10): the i8 operands are stored in
// MFMA fragment order so the GEMM needs NO LDS at all.
//   For a matrix row r (A) / col c (B), k element k:
//     blk = r>>5, rw = r&31, kt = k>>5, half = (k>>4)&1, byte = k&15
//     addr = blk*131072 + kt*1024 + half*512 + rw*16 + byte
//   A fragment for (blk, kt) is 1024 contiguous bytes; GEMM lane l reads
//   16 B at +l*16  (l>>5 = half = k-chunk, l&31 = rw)  -- exactly the
//   mfma_i32_32x32x32_i8 operand map verified by the passing r6 kernel.
// ---------------------------------------------------------------------------

// cvt: x-quant wave-per-row (blocks [0,1024), 8 waves/block) + w-sign
// (blocks [1024,3072)); both write fragment-major 16-B chunks.
__global__ void __launch_bounds__(512)
cvt_fused_i8_kernel(const float* __restrict__ x,
                    const float* __restrict__ w,
                    signed char* __restrict__ xb,
                    signed char* __restrict__ wb,
                    float* __restrict__ row_scale) {
    const int b   = blockIdx.x;
    const int tid = threadIdx.x;
    if (b < 1024) {
        const int wv   = tid >> 6;             // 0..7
        const int lane = tid & 63;
        const int row  = b * 8 + wv;           // 0..8191
        const float* xr = x + (size_t)row * K_DIM;

        // pass 1: absmax (coalesced 1KB/wave-instr)
        float am = 0.f;
#pragma unroll
        for (int i = 0; i < 16; ++i) {
            const float4 v = *(const float4*)(xr + lane * 4 + i * 256);
            am = fmaxf(am, fmaxf(fmaxf(fabsf(v.x), fabsf(v.y)),
                                 fmaxf(fabsf(v.z), fabsf(v.w))));
        }
#pragma unroll
        for (int off = 32; off > 0; off >>= 1)
            am = fmaxf(am, __shfl_xor(am, off));
        am = fmaxf(am, 1e-30f);
        const float inv = 127.f / am;

        // pass 2: lane owns 16-elem chunks ch = i*64+lane (L1/L2-hot reread)
        signed char* xo = xb + (size_t)(row >> 5) * 131072 + (row & 31) * 16;
#pragma unroll
        for (int i = 0; i < 4; ++i) {
            const int ch = i * 64 + lane;          // 0..255
            const float* src = xr + ch * 16;
            union { signed char c[16]; uint4 u4; } r;
#pragma unroll
            for (int j = 0; j < 16; ++j) {
                int q = (int)rintf(src[j] * inv);
                q = q > 127 ? 127 : (q < -127 ? -127 : q);
                r.c[j] = (signed char)q;
            }
            *(uint4*)(xo + (ch >> 1) * 1024 + (ch & 1) * 512) = r.u4;
        }
        if (lane == 0) row_scale[row] = am * (1.f / 127.f);
    } else {
        // w sign: 1,048,576 threads, each 16 consecutive k of one col
        const size_t gt = (size_t)(b - 1024) * 512 + tid;
        const int col = (int)(gt >> 8);            // 0..4095
        const int ch  = (int)(gt & 255);           // 0..255
        const float* src = w + (size_t)col * K_DIM + ch * 16;
        union { signed char c[16]; uint4 u4; } r;
#pragma unroll
        for (int j = 0; j < 16; ++j) {
            const float a = src[j];
            r.c[j] = (signed char)((a > 0.f) - (a < 0.f));
        }
        *(uint4*)(wb + (size_t)(col >> 5) * 131072 +
                  (ch >> 1) * 1024 + (ch & 1) * 512 + (col & 31) * 16) = r.u4;
    }
}

// ---------------------------------------------------------------------------
// i8 GEMM round-10: ZERO-LDS, register-ping-pong, barrier-free.
// r2-r6 proved period = MFMA-pipe + LDS-port (serialized, schedule-invariant).
// Fragment-major operands remove the LDS term entirely: 12 coalesced
// global_load_dwordx4 per tile per wave (L2-resident panels, ~728 cyc/CU-tile
// of L2 BW < 1170 cyc pipe), no barriers -> waves free-run, VMEM overlaps
// MFMA (m114). Unroll-2 role swap = no register copies; compiler auto-emits
// counted vmcnt(12) (never 0 mid-loop).
// 256x256 block tile, 8 waves (2M x 4N), wave C = 128x64, BK=64 (2 k-steps).
// ---------------------------------------------------------------------------
__global__ void __launch_bounds__(512, 2)
gemm_i8_kernel(const signed char* __restrict__ A,
               const signed char* __restrict__ B,
               const float* __restrict__ bias,
               const float* __restrict__ scale,
               const float* __restrict__ row_scale,
               float* __restrict__ out) {
    const int tid  = threadIdx.x;
    const int lane = tid & 63;
    const int wave = tid >> 6;   // 0..7
    const int wm = wave >> 2;    // 0..1 : 128-row half
    const int wn = wave & 3;     // 0..3 : 64-col slice
    const int r5 = lane & 31;
    const int hi = lane >> 5;

    // XCD-bijective swizzle: 512 blocks = 8 XCDs x 64; n-fast within XCD
    const int bid = blockIdx.x;
    const int swz = (bid & 7) * 64 + (bid >> 3);
    const int rowBase = (swz >> 4) * 256;
    const int colBase = (swz & 15) * 256;

    // fragment-major base pointers: frag(blk,kt) @ blk*131072 + kt*1024 + l*16
    const signed char* pA0 =
        A + (size_t)((rowBase >> 5) + wm * 4) * 131072 + lane * 16;
    const signed char* pA1 = pA0 + 131072;
    const signed char* pA2 = pA0 + 2 * 131072;
    const signed char* pA3 = pA0 + 3 * 131072;
    const signed char* pB0 =
        B + (size_t)((colBase >> 5) + wn * 2) * 131072 + lane * 16;
    const signed char* pB1 = pB0 + 131072;

    intx16 acc[4][2] = {};
    intx4 a0[4][2], b0[2][2], a1[4][2], b1[2][2];

#define LOADSET(sa, sb, koff)                                                  \
    do {                                                                       \
        sa[0][0] = *(const intx4*)(pA0 + (koff));                              \
        sa[0][1] = *(const intx4*)(pA0 + (koff) + 1024);                       \
        sa[1][0] = *(const intx4*)(pA1 + (koff));                              \
        sa[1][1] = *(const intx4*)(pA1 + (koff) + 1024);                       \
        sa[2][0] = *(const intx4*)(pA2 + (koff));                              \
        sa[2][1] = *(const intx4*)(pA2 + (koff) + 1024);                       \
        sa[3][0] = *(const intx4*)(pA3 + (koff));                              \
        sa[3][1] = *(const intx4*)(pA3 + (koff) + 1024);                       \
        sb[0][0] = *(const intx4*)(pB0 + (koff));                              \
        sb[0][1] = *(const intx4*)(pB0 + (koff) + 1024);                       \
        sb[1][0] = *(const intx4*)(pB1 + (koff));                              \
        sb[1][1] = *(const intx4*)(pB1 + (koff) + 1024);                       \
    } while (0)

#define MFMASET(sa, sb)                                                        \
    do {                                                                       \
        __builtin_amdgcn_s_setprio(1);                                         \
        _Pragma("unroll") for (int ks = 0; ks < 2; ++ks)                       \
            _Pragma("unroll") for (int mt = 0; mt < 4; ++mt)                   \
                _Pragma("unroll") for (int nt = 0; nt < 2; ++nt)               \
                    acc[mt][nt] = __builtin_amdgcn_mfma_i32_32x32x32_i8(       \
                        sa[mt][ks], sb[nt][ks], acc[mt][nt], 0, 0, 0);         \
        __builtin_amdgcn_s_setprio(0);                                         \
    } while (0)

    // prologue: tile 0 into set0
    LOADSET(a0, b0, 0);

#pragma unroll 1
    for (int i = 0; i < 32; ++i) {
        const int koff = i * 4096;               // tile 2i at koff
        LOADSET(a1, b1, koff + 2048);            // tile 2i+1
        __builtin_amdgcn_sched_barrier(0);
        MFMASET(a0, b0);                          // waits vmcnt(12) [counted]
        __builtin_amdgcn_sched_barrier(0);
        if (i < 31) LOADSET(a0, b0, koff + 4096);  // tile 2i+2
        __builtin_amdgcn_sched_barrier(0);
        MFMASET(a1, b1);
        __builtin_amdgcn_sched_barrier(0);
    }
#undef LOADSET
#undef MFMASET

    // ---- epilogue: 32x32 C/D layout col=lane&31, row=(reg&3)+8*(reg>>2)+4*hi
    const float s = scale[0];
#pragma unroll
    for (int nt = 0; nt < 2; ++nt) {
        const int gcol = colBase + wn * 64 + nt * 32 + r5;
        const float bv = bias[gcol];
#pragma unroll
        for (int mt = 0; mt < 4; ++mt) {
#pragma unroll
            for (int q = 0; q < 4; ++q) {
                const int row0 = rowBase + wm * 128 + mt * 32 + q * 8 + hi * 4;
                const float4 rs4 = *(const float4*)(row_scale + row0);
                const float rs[4] = {rs4.x, rs4.y, rs4.z, rs4.w};
#pragma unroll
                for (int r = 0; r < 4; ++r)
                    __builtin_nontemporal_store(
                        s * ((float)acc[mt][nt][q * 4 + r] * rs[r] + bv),
                        out + (size_t)(row0 + r) * N_DIM + gcol);
            }
        }
    }
}

// slow but correct fp32 fallback (only if workspace is too small)
__global__ void fallback_kernel(const float* __restrict__ x,
                                const float* __restrict__ w,
                                const float* __restrict__ bias,
                                const float* __restrict__ scale,
                                float* __restrict__ out) {
    int col = blockIdx.x * 64 + (threadIdx.x & 63);
    int row = blockIdx.y * 4 + (threadIdx.x >> 6);
    const float* xr = x + (size_t)row * K_DIM;
    const float* wr = w + (size_t)col * K_DIM;
    float acc = 0.f;
    for (int k = 0; k < K_DIM; k += 4) {
        float4 a = *(const float4*)(xr + k);
        float4 b = *(const float4*)(wr + k);
        acc += a.x * (b.x > 0.f ? 1.f : (b.x < 0.f ? -1.f : 0.f));
        acc += a.y * (b.y > 0.f ? 1.f : (b.y < 0.f ? -1.f : 0.f));
        acc += a.z * (b.z > 0.f ? 1.f : (b.z < 0.f ? -1.f : 0.f));
        acc += a.w * (b.w > 0.f ? 1.f : (b.w < 0.f ? -1.f : 0.f));
    }
    out[(size_t)row * N_DIM + col] = scale[0] * (acc + bias[col]);
}

extern "C" void kernel_launch(void* const* d_in, const int* in_sizes, int n_in,
                              void* d_out, int out_size, void* d_ws, size_t ws_size,
                              hipStream_t stream) {
    const float* x     = (const float*)d_in[0];
    const float* w     = (const float*)d_in[1];
    const float* bias  = (const float*)d_in[2];
    const float* scale = (const float*)d_in[3];
    float* out = (float*)d_out;

    const size_t xb_bytes = (size_t)M_DIM * K_DIM;          // 32 MiB
    const size_t wb_bytes = (size_t)N_DIM * K_DIM;          // 16 MiB
    const size_t need = xb_bytes + wb_bytes + M_DIM * sizeof(float);

    if (ws_size >= need) {
        signed char* xb = (signed char*)d_ws;
        signed char* wb = xb + xb_bytes;
        float* row_scale = (float*)(wb + wb_bytes);
        cvt_fused_i8_kernel<<<dim3(3072), 512, 0, stream>>>(
            x, w, xb, wb, row_scale);
        gemm_i8_kernel<<<dim3((M_DIM / 256) * (N_DIM / 256)), 512, 0, stream>>>(
            xb, wb, bias, scale, row_scale, out);
    } else {
        dim3 grid(N_DIM / 64, M_DIM / 4);
        fallback_kernel<<<grid, 256, 0, stream>>>(x, w, bias, scale, out);
    }
}

// Round 11
// 424.212 us; speedup vs baseline: 1.0592x; 1.0592x over previous
//
#include <hip/hip_runtime.h>
#include <hip/hip_bf16.h>
#include <stdint.h>

#define M_DIM 8192   // rows of x / out
#define K_DIM 4096   // inner dim
#define N_DIM 4096   // cols of out = rows of W

typedef int intx4  __attribute__((ext_vector_type(4)));
typedef int intx16 __attribute__((ext_vector_type(16)));

// ---------------------------------------------------------------------------
// cvt (r9, verified passing): x-quant one wave/row + w-sign grid-strided.
// ---------------------------------------------------------------------------
__global__ void __launch_bounds__(512)
cvt_fused_i8_kernel(const float* __restrict__ x,
                    const float* __restrict__ w,
                    signed char* __restrict__ xb,
                    signed char* __restrict__ wb,
                    float* __restrict__ row_scale) {
    const int b   = blockIdx.x;
    const int tid = threadIdx.x;
    if (b < 1024) {
        const int wv   = tid >> 6;             // 0..7
        const int lane = tid & 63;
        const int row  = b * 8 + wv;           // 0..8191
        const float* xr = x + (size_t)row * K_DIM;

        float am = 0.f;
#pragma unroll
        for (int i = 0; i < 16; ++i) {
            const float4 v = *(const float4*)(xr + lane * 4 + i * 256);
            am = fmaxf(am, fmaxf(fmaxf(fabsf(v.x), fabsf(v.y)),
                                 fmaxf(fabsf(v.z), fabsf(v.w))));
        }
#pragma unroll
        for (int off = 32; off > 0; off >>= 1)
            am = fmaxf(am, __shfl_xor(am, off));
        am = fmaxf(am, 1e-30f);
        const float inv = 127.f / am;

        signed char* xo = xb + (size_t)row * K_DIM;
#pragma unroll
        for (int i = 0; i < 16; ++i) {
            const float4 v = *(const float4*)(xr + lane * 4 + i * 256);
            const float vf[4] = {v.x, v.y, v.z, v.w};
            union { signed char c[4]; uint32_t u; } r;
#pragma unroll
            for (int k = 0; k < 4; ++k) {
                int q = (int)rintf(vf[k] * inv);
                q = q > 127 ? 127 : (q < -127 ? -127 : q);
                r.c[k] = (signed char)q;
            }
            *(uint32_t*)(xo + lane * 4 + i * 256) = r.u;
        }
        if (lane == 0) row_scale[row] = am * (1.f / 127.f);
    } else {
        const int bw = b - 1024;                      // 0..2047
        const size_t t0 = (size_t)bw * 512 + tid;     // float4 index base
#pragma unroll
        for (int i = 0; i < 4; ++i) {
            const size_t idx = t0 + (size_t)i * 1048576;
            const float4 a = *(const float4*)(w + idx * 4);
            union { signed char s[4]; uint32_t u; } r;
            r.s[0] = (a.x > 0.f) - (a.x < 0.f);
            r.s[1] = (a.y > 0.f) - (a.y < 0.f);
            r.s[2] = (a.z > 0.f) - (a.z < 0.f);
            r.s[3] = (a.w > 0.f) - (a.w < 0.f);
            *(uint32_t*)(wb + idx * 4) = r.u;
        }
    }
}

__device__ __forceinline__ void gld_lds16(const void* g, void* l) {
    __builtin_amdgcn_global_load_lds(
        (const __attribute__((address_space(1))) void*)g,
        (__attribute__((address_space(3))) void*)l,
        16, 0, 0);
}

// ---------------------------------------------------------------------------
// i8 GEMM round-11: ZERO-WAIT MFMA CLUSTERS (r2 cross-tile prefetch + r6
// k-split + fixed swizzle + m201-style mid-tile vmcnt+barrier residency).
//
// Per tile t (read slot sr=t%3, prefetch slot (t+1)%3, stage slot (t+2)%3):
//   [STAGE(t+2): 4 gld_lds] [k1 reads oa/ob from sr]       <- issue only
//   cluster A: 8 MFMA on (fa,fb) PRELOADED during t-1      <- NO lgkm wait
//   vmcnt(4) + s_barrier                                    <- slot t+1 now
//                                                              resident for
//                                                              ALL waves
//   [k0' reads (ga,gb) for tile t+1 from slot (t+1)%3]     <- issue only
//   cluster B: 8 MFMA on (oa,ob)  [lgkmcnt(6): oa/ob issued 585 cyc ago]
//   s_barrier                                               <- tile boundary
// Every ds_read retires >= 1 full MFMA cluster (585 cyc/SIMD) before its
// consumer; no wave ever stalls on a fresh read burst.
//
// Race audit (cross-wave):
//  1. k1 reads of slot t%3 at t top: written by t-2-top glds, drained for
//     ALL waves by the t-1 MID vmcnt(4)+barrier (only t-1-top glds, slot
//     (t+1)%3, may remain). Reads occur after t-1 END barrier. Safe.
//  2. k0' reads of slot (t+1)%3 after t MID barrier: vmcnt(4) leaves only
//     t-top glds (slot (t+2)%3) outstanding per wave; barrier publishes. Safe.
//  3. STAGE at t top writes slot (t+2)%3 == (t-1)%3: its last reads (t-1's
//     k1, consumed by t-1 cluster B; t-1's k0, consumed by t-1 cluster A)
//     retired before the t-1 END barrier; STAGE issues after it. Safe.
//  4. Epilogue: t<=61 vmcnt(4); t==62 vmcnt(0) (drains tile-63 glds before
//     its k0' reads); t==63 stages/prefetches nothing.
//
// Swizzle: r6's verified algebra. f(row)=((row>>1)&3)^(((row>>4)&1)<<1);
// write side (lane>>3)&3 ^ (wave&1)<<1; read side ((r5>>1)&3)^(((r5>>4)&1)<<1).
// Geometry: 256x256 tile, BK=64, 8 waves (2Mx4N), wave C=128x64 via
// mfma_i32_32x32x32_i8; LDS ring-3 = 96 KiB, 2 waves/SIMD.
// ---------------------------------------------------------------------------
__global__ void __launch_bounds__(512, 2)
gemm_i8_kernel(const signed char* __restrict__ A,
               const signed char* __restrict__ B,
               const float* __restrict__ bias,
               const float* __restrict__ scale,
               const float* __restrict__ row_scale,
               float* __restrict__ out) {
    __shared__ __attribute__((aligned(16))) signed char sA[3][256 * 64];
    __shared__ __attribute__((aligned(16))) signed char sB[3][256 * 64];

    const int tid  = threadIdx.x;
    const int lane = tid & 63;
    const int wave = tid >> 6;   // 0..7
    const int wm = wave >> 2;    // 0..1 : 128-row half
    const int wn = wave & 3;     // 0..3 : 64-col slice
    const int r5 = lane & 31;
    const int hi = lane >> 5;

    // XCD-bijective swizzle: 512 blocks = 8 XCDs x 64; n-fast within XCD
    const int bid = blockIdx.x;
    const int swz = (bid & 7) * 64 + (bid >> 3);
    const int rowBase = (swz >> 4) * 256;
    const int colBase = (swz & 15) * 256;

    // ---- staging: linear LDS dest, pre-swizzled global chunk ----
    const int sc   = (lane & 3) ^ ((lane >> 3) & 3) ^ ((wave & 1) << 1);
    const int srow = wave * 16 + (lane >> 2);
    const signed char* gA0 = A + (size_t)(rowBase + srow) * K_DIM + sc * 16;
    const signed char* gA1 = gA0 + (size_t)128 * K_DIM;
    const signed char* gB0 = B + (size_t)(colBase + srow) * K_DIM + sc * 16;
    const signed char* gB1 = gB0 + (size_t)128 * K_DIM;
    const int ldsR0 = wave * 1024;
    const int ldsR1 = 8192 + wave * 1024;

    // ---- fragment read offsets (row=lane&31, chunk=hi+2*kstep, XORed) ----
    const int fsw = ((r5 >> 1) & 3) ^ (((r5 >> 4) & 1) << 1);
    const int ckE = ((hi + 0) ^ fsw) * 16;    // k-step 0
    const int ckO = ((hi + 2) ^ fsw) * 16;    // k-step 1
    const int aOff = (wm * 128 + r5) * 64;    // + mt*2048
    const int bOff = (wn * 64 + r5) * 64;     // + nt*2048

    const signed char* sA0 = &sA[0][0];
    const signed char* sB0 = &sB[0][0];

    intx16 acc[4][2] = {};
    intx4 fa[4], fb[2], ga[4], gb[2], oa[4], ob[2];

#define STAGE(slotB, kt)                                                       \
    do {                                                                       \
        const size_t kg_ = (size_t)(kt) * 64;                                  \
        signed char* pA_ = (signed char*)sA0 + (slotB);                        \
        signed char* pB_ = (signed char*)sB0 + (slotB);                        \
        gld_lds16(gA0 + kg_, pA_ + ldsR0);                                     \
        gld_lds16(gA1 + kg_, pA_ + ldsR1);                                     \
        gld_lds16(gB0 + kg_, pB_ + ldsR0);                                     \
        gld_lds16(gB1 + kg_, pB_ + ldsR1);                                     \
    } while (0)

#define CLUSTER(CA, CB)                                                        \
    do {                                                                       \
        __builtin_amdgcn_s_setprio(1);                                         \
        _Pragma("unroll") for (int mt = 0; mt < 4; ++mt)                       \
            _Pragma("unroll") for (int nt = 0; nt < 2; ++nt)                   \
                acc[mt][nt] = __builtin_amdgcn_mfma_i32_32x32x32_i8(           \
                    CA[mt], CB[nt], acc[mt][nt], 0, 0, 0);                     \
        __builtin_amdgcn_s_setprio(0);                                         \
    } while (0)

    // TILE body; CA/CB = preloaded k0 frags for tile t; NA/NB = k0' dest.
#define TILE(t, srB, CA, CB, NA, NB)                                           \
    do {                                                                       \
        const signed char* sAb = sA0 + (srB);                                  \
        const signed char* sBb = sB0 + (srB);                                  \
        if ((t) <= 61) {                                                       \
            const int swB_ = (srB) >= 16384 ? (srB)-16384 : (srB)+32768;       \
            STAGE(swB_, (t) + 2);                                              \
        }                                                                      \
        _Pragma("unroll") for (int mt = 0; mt < 4; ++mt)                       \
            oa[mt] = *(const intx4*)(sAb + aOff + mt * 2048 + ckO);            \
        _Pragma("unroll") for (int nt = 0; nt < 2; ++nt)                       \
            ob[nt] = *(const intx4*)(sBb + bOff + nt * 2048 + ckO);            \
        __builtin_amdgcn_sched_barrier(0);                                     \
        CLUSTER(CA, CB);                  /* zero lgkm wait */                 \
        __builtin_amdgcn_sched_barrier(0);                                     \
        if ((t) <= 61)      asm volatile("s_waitcnt vmcnt(4)" ::: "memory");   \
        else if ((t) == 62) asm volatile("s_waitcnt vmcnt(0)" ::: "memory");   \
        __builtin_amdgcn_s_barrier();     /* slot t+1 published */             \
        if ((t) < 63) {                                                        \
            const int nxB_ = (srB) == 32768 ? 0 : (srB) + 16384;               \
            const signed char* sAn = sA0 + nxB_;                               \
            const signed char* sBn = sB0 + nxB_;                               \
            _Pragma("unroll") for (int mt = 0; mt < 4; ++mt)                   \
                NA[mt] = *(const intx4*)(sAn + aOff + mt * 2048 + ckE);        \
            _Pragma("unroll") for (int nt = 0; nt < 2; ++nt)                   \
                NB[nt] = *(const intx4*)(sBn + bOff + nt * 2048 + ckE);        \
        }                                                                      \
        __builtin_amdgcn_sched_barrier(0);                                     \
        CLUSTER(oa, ob);                  /* lgkmcnt(6), already met */        \
        __builtin_amdgcn_sched_barrier(0);                                     \
        __builtin_amdgcn_s_barrier();     /* tile boundary */                  \
    } while (0)

    // ---- prologue: stage tiles 0,1; preload k0 frags of tile 0 ----
    STAGE(0, 0);
    STAGE(16384, 1);
    asm volatile("s_waitcnt vmcnt(4)" ::: "memory");   // tile 0 landed
    __builtin_amdgcn_s_barrier();
#pragma unroll
    for (int mt = 0; mt < 4; ++mt)
        fa[mt] = *(const intx4*)(sA0 + aOff + mt * 2048 + ckE);
#pragma unroll
    for (int nt = 0; nt < 2; ++nt)
        fb[nt] = *(const intx4*)(sB0 + bOff + nt * 2048 + ckE);

    int srB = 0;
#pragma unroll 1
    for (int tt = 0; tt < 32; ++tt) {
        const int t0 = tt * 2;
        TILE(t0,     srB, fa, fb, ga, gb);
        srB = (srB == 32768) ? 0 : srB + 16384;
        TILE(t0 + 1, srB, ga, gb, fa, fb);
        srB = (srB == 32768) ? 0 : srB + 16384;
    }
#undef TILE
#undef CLUSTER
#undef STAGE

    // ---- epilogue: 32x32 C/D layout col=lane&31, row=(reg&3)+8*(reg>>2)+4*hi
    const float s = scale[0];
#pragma unroll
    for (int nt = 0; nt < 2; ++nt) {
        const int gcol = colBase + wn * 64 + nt * 32 + r5;
        const float bv = bias[gcol];
#pragma unroll
        for (int mt = 0; mt < 4; ++mt) {
#pragma unroll
            for (int q = 0; q < 4; ++q) {
                const int row0 = rowBase + wm * 128 + mt * 32 + q * 8 + hi * 4;
                const float4 rs4 = *(const float4*)(row_scale + row0);
                const float rs[4] = {rs4.x, rs4.y, rs4.z, rs4.w};
#pragma unroll
                for (int r = 0; r < 4; ++r)
                    __builtin_nontemporal_store(
                        s * ((float)acc[mt][nt][q * 4 + r] * rs[r] + bv),
                        out + (size_t)(row0 + r) * N_DIM + gcol);
            }
        }
    }
}

// slow but correct fp32 fallback (only if workspace is too small)
__global__ void fallback_kernel(const float* __restrict__ x,
                                const float* __restrict__ w,
                                const float* __restrict__ bias,
                                const float* __restrict__ scale,
                                float* __restrict__ out) {
    int col = blockIdx.x * 64 + (threadIdx.x & 63);
    int row = blockIdx.y * 4 + (threadIdx.x >> 6);
    const float* xr = x + (size_t)row * K_DIM;
    const float* wr = w + (size_t)col * K_DIM;
    float acc = 0.f;
    for (int k = 0; k < K_DIM; k += 4) {
        float4 a = *(const float4*)(xr + k);
        float4 b = *(const float4*)(wr + k);
        acc += a.x * (b.x > 0.f ? 1.f : (b.x < 0.f ? -1.f : 0.f));
        acc += a.y * (b.y > 0.f ? 1.f : (b.y < 0.f ? -1.f : 0.f));
        acc += a.z * (b.z > 0.f ? 1.f : (b.z < 0.f ? -1.f : 0.f));
        acc += a.w * (b.w > 0.f ? 1.f : (b.w < 0.f ? -1.f : 0.f));
    }
    out[(size_t)row * N_DIM + col] = scale[0] * (acc + bias[col]);
}

extern "C" void kernel_launch(void* const* d_in, const int* in_sizes, int n_in,
                              void* d_out, int out_size, void* d_ws, size_t ws_size,
                              hipStream_t stream) {
    const float* x     = (const float*)d_in[0];
    const float* w     = (const float*)d_in[1];
    const float* bias  = (const float*)d_in[2];
    const float* scale = (const float*)d_in[3];
    float* out = (float*)d_out;

    const size_t xb_bytes = (size_t)M_DIM * K_DIM;          // 32 MiB
    const size_t wb_bytes = (size_t)N_DIM * K_DIM;          // 16 MiB
    const size_t need = xb_bytes + wb_bytes + M_DIM * sizeof(float);

    if (ws_size >= need) {
        signed char* xb = (signed char*)d_ws;
        signed char* wb = xb + xb_bytes;
        float* row_scale = (float*)(wb + wb_bytes);
        cvt_fused_i8_kernel<<<dim3(3072), 512, 0, stream>>>(
            x, w, xb, wb, row_scale);
        gemm_i8_kernel<<<dim3((M_DIM / 256) * (N_DIM / 256)), 512, 0, stream>>>(
            xb, wb, bias, scale, row_scale, out);
    } else {
        dim3 grid(N_DIM / 64, M_DIM / 4);
        fallback_kernel<<<grid, 256, 0, stream>>>(x, w, bias, scale, out);
    }
}

// Round 12
// 419.008 us; speedup vs baseline: 1.0723x; 1.0124x over previous
//
#include <hip/hip_runtime.h>
#include <hip/hip_bf16.h>
#include <stdint.h>

#define M_DIM 8192   // rows of x / out
#define K_DIM 4096   // inner dim
#define N_DIM 4096   // cols of out = rows of W

typedef int intx4  __attribute__((ext_vector_type(4)));
typedef int intx16 __attribute__((ext_vector_type(16)));

// ---------------------------------------------------------------------------
// cvt (r9, verified passing): x-quant one wave/row + w-sign grid-strided.
// ---------------------------------------------------------------------------
__global__ void __launch_bounds__(512)
cvt_fused_i8_kernel(const float* __restrict__ x,
                    const float* __restrict__ w,
                    signed char* __restrict__ xb,
                    signed char* __restrict__ wb,
                    float* __restrict__ row_scale) {
    const int b   = blockIdx.x;
    const int tid = threadIdx.x;
    if (b < 1024) {
        const int wv   = tid >> 6;             // 0..7
        const int lane = tid & 63;
        const int row  = b * 8 + wv;           // 0..8191
        const float* xr = x + (size_t)row * K_DIM;

        float am = 0.f;
#pragma unroll
        for (int i = 0; i < 16; ++i) {
            const float4 v = *(const float4*)(xr + lane * 4 + i * 256);
            am = fmaxf(am, fmaxf(fmaxf(fabsf(v.x), fabsf(v.y)),
                                 fmaxf(fabsf(v.z), fabsf(v.w))));
        }
#pragma unroll
        for (int off = 32; off > 0; off >>= 1)
            am = fmaxf(am, __shfl_xor(am, off));
        am = fmaxf(am, 1e-30f);
        const float inv = 127.f / am;

        signed char* xo = xb + (size_t)row * K_DIM;
#pragma unroll
        for (int i = 0; i < 16; ++i) {
            const float4 v = *(const float4*)(xr + lane * 4 + i * 256);
            const float vf[4] = {v.x, v.y, v.z, v.w};
            union { signed char c[4]; uint32_t u; } r;
#pragma unroll
            for (int k = 0; k < 4; ++k) {
                int q = (int)rintf(vf[k] * inv);
                q = q > 127 ? 127 : (q < -127 ? -127 : q);
                r.c[k] = (signed char)q;
            }
            *(uint32_t*)(xo + lane * 4 + i * 256) = r.u;
        }
        if (lane == 0) row_scale[row] = am * (1.f / 127.f);
    } else {
        const int bw = b - 1024;                      // 0..2047
        const size_t t0 = (size_t)bw * 512 + tid;     // float4 index base
#pragma unroll
        for (int i = 0; i < 4; ++i) {
            const size_t idx = t0 + (size_t)i * 1048576;
            const float4 a = *(const float4*)(w + idx * 4);
            union { signed char s[4]; uint32_t u; } r;
            r.s[0] = (a.x > 0.f) - (a.x < 0.f);
            r.s[1] = (a.y > 0.f) - (a.y < 0.f);
            r.s[2] = (a.z > 0.f) - (a.z < 0.f);
            r.s[3] = (a.w > 0.f) - (a.w < 0.f);
            *(uint32_t*)(wb + idx * 4) = r.u;
        }
    }
}

__device__ __forceinline__ void gld_lds16(const void* g, void* l) {
    __builtin_amdgcn_global_load_lds(
        (const __attribute__((address_space(1))) void*)g,
        (__attribute__((address_space(3))) void*)l,
        16, 0, 0);
}

// ---------------------------------------------------------------------------
// i8 GEMM round-12: ZERO-WAIT CLUSTERS + RING-4 (r11 minus its flaw).
// r11 regressed only because ring-3 forced a mid-tile vmcnt+barrier. Ring-4
// (prefetch distance 3) makes the EXISTING end-of-tile vmcnt(4)+barrier
// publish slots t+1 AND t+2 to all waves (after vmcnt(4) only tile-t's own
// 4 glds remain outstanding). So tile t+1 runs with r6's sync cost (ONE
// barrier + ONE counted vmcnt per tile) and r11's zero-wait clusters:
//   top:  STAGE(t+3) + k1 reads (oa/ob) from slot t
//   cluster A on (CA,CB) preloaded during tile t-1   <- NO lgkm wait
//   mid:  k0' reads (NA/NB) for tile t+1 from slot t+1  <- resident, no sync
//   cluster B on (oa,ob)    <- issued one full cluster (~585 cyc) earlier
//   end:  vmcnt(4) [t<=60] / vmcnt(0) [t==61]; s_barrier
//
// Race audit (cross-wave):
//  1. STAGE at t targets slot (t+3)&3 == (t-1)&3: its readers (t-1's k1 at
//     t-1 top; t-1's CA preloaded at t-2 mid) retired into registers before
//     t-1's end barrier; STAGE issues after it. Safe.
//  2. k1 reads at t of slot t&3 (staged t-3) and k0' reads at t of slot
//     (t+1)&3 (staged t-2): at t-1's end, vmcnt(4) leaves only t-1's glds
//     outstanding -> both slots landed; barrier publishes. Safe.
//  3. Epilogue: stages stop at t=60 (slot 63). t=60 end vmcnt(4) -> slot 62
//     landed; t=61 end vmcnt(0) -> slot 63 landed; t>=62 no waits needed.
//  4. Prologue: stage slots 0,1,2; vmcnt(4) -> slots 0,1 resident; barrier;
//     preload k0 of tile 0. Tile-0 mid reads slot 1 (resident).
//
// Geometry/swizzle identical to r6 (verified): 256x256 tile, BK=64, 8 waves
// (2Mx4N), wave C=128x64, mfma_i32_32x32x32_i8; LDS 4x(16K+16K)=128 KiB;
// f(row)=((row>>1)&3)^(((row>>4)&1)<<1) both-sides.
// Registers: 18 frag intx4 (72) + acc 128 + addr ~20 ≈ 220 -> 2 waves/SIMD.
// ---------------------------------------------------------------------------
__global__ void __launch_bounds__(512, 2)
gemm_i8_kernel(const signed char* __restrict__ A,
               const signed char* __restrict__ B,
               const float* __restrict__ bias,
               const float* __restrict__ scale,
               const float* __restrict__ row_scale,
               float* __restrict__ out) {
    __shared__ __attribute__((aligned(16))) signed char sA[4][256 * 64];
    __shared__ __attribute__((aligned(16))) signed char sB[4][256 * 64];

    const int tid  = threadIdx.x;
    const int lane = tid & 63;
    const int wave = tid >> 6;   // 0..7
    const int wm = wave >> 2;    // 0..1 : 128-row half
    const int wn = wave & 3;     // 0..3 : 64-col slice
    const int r5 = lane & 31;
    const int hi = lane >> 5;

    // XCD-bijective swizzle: 512 blocks = 8 XCDs x 64; n-fast within XCD
    const int bid = blockIdx.x;
    const int swz = (bid & 7) * 64 + (bid >> 3);
    const int rowBase = (swz >> 4) * 256;
    const int colBase = (swz & 15) * 256;

    // ---- staging: linear LDS dest, pre-swizzled global chunk ----
    const int sc   = (lane & 3) ^ ((lane >> 3) & 3) ^ ((wave & 1) << 1);
    const int srow = wave * 16 + (lane >> 2);
    const signed char* gA0 = A + (size_t)(rowBase + srow) * K_DIM + sc * 16;
    const signed char* gA1 = gA0 + (size_t)128 * K_DIM;
    const signed char* gB0 = B + (size_t)(colBase + srow) * K_DIM + sc * 16;
    const signed char* gB1 = gB0 + (size_t)128 * K_DIM;
    const int ldsR0 = wave * 1024;
    const int ldsR1 = 8192 + wave * 1024;

    // ---- fragment read offsets (row=lane&31, chunk=hi+2*kstep, XORed) ----
    const int fsw = ((r5 >> 1) & 3) ^ (((r5 >> 4) & 1) << 1);
    const int ckE = ((hi + 0) ^ fsw) * 16;    // k-step 0
    const int ckO = ((hi + 2) ^ fsw) * 16;    // k-step 1
    const int aOff = (wm * 128 + r5) * 64;    // + mt*2048
    const int bOff = (wn * 64 + r5) * 64;     // + nt*2048

    const signed char* sA0 = &sA[0][0];
    const signed char* sB0 = &sB[0][0];

    intx16 acc[4][2] = {};
    intx4 fa[4], fb[2], ga[4], gb[2], oa[4], ob[2];

#define STAGE(slotB, kt)                                                       \
    do {                                                                       \
        const size_t kg_ = (size_t)(kt) * 64;                                  \
        signed char* pA_ = (signed char*)sA0 + (slotB);                        \
        signed char* pB_ = (signed char*)sB0 + (slotB);                        \
        gld_lds16(gA0 + kg_, pA_ + ldsR0);                                     \
        gld_lds16(gA1 + kg_, pA_ + ldsR1);                                     \
        gld_lds16(gB0 + kg_, pB_ + ldsR0);                                     \
        gld_lds16(gB1 + kg_, pB_ + ldsR1);                                     \
    } while (0)

#define CLUSTER(CA, CB)                                                        \
    do {                                                                       \
        __builtin_amdgcn_s_setprio(1);                                         \
        _Pragma("unroll") for (int mt = 0; mt < 4; ++mt)                       \
            _Pragma("unroll") for (int nt = 0; nt < 2; ++nt)                   \
                acc[mt][nt] = __builtin_amdgcn_mfma_i32_32x32x32_i8(           \
                    CA[mt], CB[nt], acc[mt][nt], 0, 0, 0);                     \
        __builtin_amdgcn_s_setprio(0);                                         \
    } while (0)

    // TILE: CA/CB = k0 frags preloaded last tile; NA/NB = next tile's k0 dest
#define TILE(t, CA, CB, NA, NB)                                                \
    do {                                                                       \
        const int sIdxB = ((t) & 3) * 16384;                                   \
        const signed char* sAb = sA0 + sIdxB;                                  \
        const signed char* sBb = sB0 + sIdxB;                                  \
        if ((t) <= 60) STAGE((((t) + 3) & 3) * 16384, (t) + 3);                \
        _Pragma("unroll") for (int mt = 0; mt < 4; ++mt)                       \
            oa[mt] = *(const intx4*)(sAb + aOff + mt * 2048 + ckO);            \
        _Pragma("unroll") for (int nt = 0; nt < 2; ++nt)                       \
            ob[nt] = *(const intx4*)(sBb + bOff + nt * 2048 + ckO);            \
        __builtin_amdgcn_sched_barrier(0);                                     \
        CLUSTER(CA, CB);                  /* zero wait */                      \
        __builtin_amdgcn_sched_barrier(0);                                     \
        if ((t) < 63) {                                                        \
            const int nxB_ = (((t) + 1) & 3) * 16384;                          \
            const signed char* sAn = sA0 + nxB_;                               \
            const signed char* sBn = sB0 + nxB_;                               \
            _Pragma("unroll") for (int mt = 0; mt < 4; ++mt)                   \
                NA[mt] = *(const intx4*)(sAn + aOff + mt * 2048 + ckE);        \
            _Pragma("unroll") for (int nt = 0; nt < 2; ++nt)                   \
                NB[nt] = *(const intx4*)(sBn + bOff + nt * 2048 + ckE);        \
        }                                                                      \
        __builtin_amdgcn_sched_barrier(0);                                     \
        CLUSTER(oa, ob);                  /* issued one cluster ago */         \
        __builtin_amdgcn_sched_barrier(0);                                     \
        if ((t) <= 60)      asm volatile("s_waitcnt vmcnt(4)" ::: "memory");   \
        else if ((t) == 61) asm volatile("s_waitcnt vmcnt(0)" ::: "memory");   \
        __builtin_amdgcn_s_barrier();                                          \
    } while (0)

    // ---- prologue: stage tiles 0,1,2; preload k0 frags of tile 0 ----
    STAGE(0, 0);
    STAGE(16384, 1);
    STAGE(32768, 2);
    asm volatile("s_waitcnt vmcnt(4)" ::: "memory");   // tiles 0,1 resident
    __builtin_amdgcn_s_barrier();
#pragma unroll
    for (int mt = 0; mt < 4; ++mt)
        fa[mt] = *(const intx4*)(sA0 + aOff + mt * 2048 + ckE);
#pragma unroll
    for (int nt = 0; nt < 2; ++nt)
        fb[nt] = *(const intx4*)(sB0 + bOff + nt * 2048 + ckE);

#pragma unroll 1
    for (int tt = 0; tt < 32; ++tt) {
        TILE(tt * 2,     fa, fb, ga, gb);
        TILE(tt * 2 + 1, ga, gb, fa, fb);
    }
#undef TILE
#undef CLUSTER
#undef STAGE

    // ---- epilogue: 32x32 C/D layout col=lane&31, row=(reg&3)+8*(reg>>2)+4*hi
    const float s = scale[0];
#pragma unroll
    for (int nt = 0; nt < 2; ++nt) {
        const int gcol = colBase + wn * 64 + nt * 32 + r5;
        const float bv = bias[gcol];
#pragma unroll
        for (int mt = 0; mt < 4; ++mt) {
#pragma unroll
            for (int q = 0; q < 4; ++q) {
                const int row0 = rowBase + wm * 128 + mt * 32 + q * 8 + hi * 4;
                const float4 rs4 = *(const float4*)(row_scale + row0);
                const float rs[4] = {rs4.x, rs4.y, rs4.z, rs4.w};
#pragma unroll
                for (int r = 0; r < 4; ++r)
                    __builtin_nontemporal_store(
                        s * ((float)acc[mt][nt][q * 4 + r] * rs[r] + bv),
                        out + (size_t)(row0 + r) * N_DIM + gcol);
            }
        }
    }
}

// slow but correct fp32 fallback (only if workspace is too small)
__global__ void fallback_kernel(const float* __restrict__ x,
                                const float* __restrict__ w,
                                const float* __restrict__ bias,
                                const float* __restrict__ scale,
                                float* __restrict__ out) {
    int col = blockIdx.x * 64 + (threadIdx.x & 63);
    int row = blockIdx.y * 4 + (threadIdx.x >> 6);
    const float* xr = x + (size_t)row * K_DIM;
    const float* wr = w + (size_t)col * K_DIM;
    float acc = 0.f;
    for (int k = 0; k < K_DIM; k += 4) {
        float4 a = *(const float4*)(xr + k);
        float4 b = *(const float4*)(wr + k);
        acc += a.x * (b.x > 0.f ? 1.f : (b.x < 0.f ? -1.f : 0.f));
        acc += a.y * (b.y > 0.f ? 1.f : (b.y < 0.f ? -1.f : 0.f));
        acc += a.z * (b.z > 0.f ? 1.f : (b.z < 0.f ? -1.f : 0.f));
        acc += a.w * (b.w > 0.f ? 1.f : (b.w < 0.f ? -1.f : 0.f));
    }
    out[(size_t)row * N_DIM + col] = scale[0] * (acc + bias[col]);
}

extern "C" void kernel_launch(void* const* d_in, const int* in_sizes, int n_in,
                              void* d_out, int out_size, void* d_ws, size_t ws_size,
                              hipStream_t stream) {
    const float* x     = (const float*)d_in[0];
    const float* w     = (const float*)d_in[1];
    const float* bias  = (const float*)d_in[2];
    const float* scale = (const float*)d_in[3];
    float* out = (float*)d_out;

    const size_t xb_bytes = (size_t)M_DIM * K_DIM;          // 32 MiB
    const size_t wb_bytes = (size_t)N_DIM * K_DIM;          // 16 MiB
    const size_t need = xb_bytes + wb_bytes + M_DIM * sizeof(float);

    if (ws_size >= need) {
        signed char* xb = (signed char*)d_ws;
        signed char* wb = xb + xb_bytes;
        float* row_scale = (float*)(wb + wb_bytes);
        cvt_fused_i8_kernel<<<dim3(3072), 512, 0, stream>>>(
            x, w, xb, wb, row_scale);
        gemm_i8_kernel<<<dim3((M_DIM / 256) * (N_DIM / 256)), 512, 0, stream>>>(
            xb, wb, bias, scale, row_scale, out);
    } else {
        dim3 grid(N_DIM / 64, M_DIM / 4);
        fallback_kernel<<<grid, 256, 0, stream>>>(x, w, bias, scale, out);
    }
}

// Round 13
// 395.172 us; speedup vs baseline: 1.1370x; 1.0603x over previous
//
#include <hip/hip_runtime.h>
#include <hip/hip_bf16.h>
#include <stdint.h>

#define M_DIM 8192   // rows of x / out
#define K_DIM 4096   // inner dim
#define N_DIM 4096   // cols of out = rows of W

typedef int intx4  __attribute__((ext_vector_type(4)));
typedef int intx16 __attribute__((ext_vector_type(16)));

// ---------------------------------------------------------------------------
// Fused conversion (round-6 verified best):
//   blocks [0, 8192):      one block per row of x -> per-row absmax-quant i8
//   blocks [8192, 16384):  w fp32 -> sign as i8, 8 elems/thread
// ---------------------------------------------------------------------------
__global__ void cvt_fused_i8_kernel(const float* __restrict__ x,
                                    const float* __restrict__ w,
                                    signed char* __restrict__ xb,
                                    signed char* __restrict__ wb,
                                    float* __restrict__ row_scale) {
    const int b   = blockIdx.x;
    const int tid = threadIdx.x;
    if (b < M_DIM) {
        // quantize one 4096-element row of x; fully coalesced loads
        __shared__ float wmax[4];
        const float* xr = x + (size_t)b * K_DIM;
        float4 v[4];
#pragma unroll
        for (int i = 0; i < 4; ++i)
            v[i] = *(const float4*)(xr + tid * 4 + i * 1024);

        float am = 0.f;
#pragma unroll
        for (int i = 0; i < 4; ++i) {
            am = fmaxf(am, fabsf(v[i].x)); am = fmaxf(am, fabsf(v[i].y));
            am = fmaxf(am, fabsf(v[i].z)); am = fmaxf(am, fabsf(v[i].w));
        }
#pragma unroll
        for (int off = 32; off > 0; off >>= 1)
            am = fmaxf(am, __shfl_xor(am, off));
        if ((tid & 63) == 0) wmax[tid >> 6] = am;
        __syncthreads();
        am = fmaxf(fmaxf(wmax[0], wmax[1]), fmaxf(wmax[2], wmax[3]));
        am = fmaxf(am, 1e-30f);

        const float inv = 127.f / am;
#pragma unroll
        for (int i = 0; i < 4; ++i) {
            union { signed char c[4]; uint32_t u; } r;
            const float* vf = (const float*)&v[i];
#pragma unroll
            for (int k = 0; k < 4; ++k) {
                int q = (int)rintf(vf[k] * inv);
                q = q > 127 ? 127 : (q < -127 ? -127 : q);
                r.c[k] = (signed char)q;
            }
            *(uint32_t*)(xb + (size_t)b * K_DIM + tid * 4 + i * 1024) = r.u;
        }
        if (tid == 0) row_scale[b] = am * (1.f / 127.f);
    } else {
        // sign(w) -> i8, 8 elems/thread
        size_t t = ((size_t)(b - M_DIM) * blockDim.x + tid) * 8;
        float4 a = *(const float4*)(w + t);
        float4 c = *(const float4*)(w + t + 4);
        union { signed char s[8]; uint2 u; } r;
        r.s[0] = (a.x > 0.f) - (a.x < 0.f); r.s[1] = (a.y > 0.f) - (a.y < 0.f);
        r.s[2] = (a.z > 0.f) - (a.z < 0.f); r.s[3] = (a.w > 0.f) - (a.w < 0.f);
        r.s[4] = (c.x > 0.f) - (c.x < 0.f); r.s[5] = (c.y > 0.f) - (c.y < 0.f);
        r.s[6] = (c.z > 0.f) - (c.z < 0.f); r.s[7] = (c.w > 0.f) - (c.w < 0.f);
        *(uint2*)(wb + t) = r.u;
    }
}

__device__ __forceinline__ void gld_lds16(const void* g, void* l) {
    __builtin_amdgcn_global_load_lds(
        (const __attribute__((address_space(1))) void*)g,
        (__attribute__((address_space(3))) void*)l,
        16, 0, 0);
}

// ---------------------------------------------------------------------------
// i8 GEMM: round-6 (measured best of 10 structural variants: 154 us,
// MfmaUtil 38.6, total 396.7). WITHIN-WAVE ILP (intra-tile k-split),
// 256x256 tile, BK=64, 8 waves (2Mx4N), wave C = 128x64 via
// mfma_i32_32x32x32_i8, LDS ring-3 (96 KiB), ONE barrier + ONE counted
// vmcnt(4) per tile. Ledger r0-r12: every schedule obeys
// period ~= MFMA-pipe (1170 cyc/CU-tile) + LDS-port term + sync; six
// attempts to overlap port and pipe (TLP, ILP, prefetch depth, setprio,
// zero-wait clusters, zero-LDS) all failed -> structural at HIP level.
// ---------------------------------------------------------------------------
__global__ void __launch_bounds__(512, 2)
gemm_i8_kernel(const signed char* __restrict__ A,
               const signed char* __restrict__ B,
               const float* __restrict__ bias,
               const float* __restrict__ scale,
               const float* __restrict__ row_scale,
               float* __restrict__ out) {
    __shared__ __attribute__((aligned(16))) signed char sA[3][256 * 64];
    __shared__ __attribute__((aligned(16))) signed char sB[3][256 * 64];

    const int tid  = threadIdx.x;
    const int lane = tid & 63;
    const int wave = tid >> 6;   // 0..7
    const int wm = wave >> 2;    // 0..1 : 128-row half
    const int wn = wave & 3;     // 0..3 : 64-col slice
    const int r5 = lane & 31;
    const int hi = lane >> 5;

    // XCD-bijective swizzle: 512 blocks = 8 XCDs x 64; n-fast within XCD
    const int bid = blockIdx.x;
    const int swz = (bid & 7) * 64 + (bid >> 3);
    const int rowBase = (swz >> 4) * 256;
    const int colBase = (swz & 15) * 256;

    // ---- staging: linear LDS dest, pre-swizzled global chunk ----
    const int sc   = (lane & 3) ^ ((lane >> 3) & 3) ^ ((wave & 1) << 1);
    const int srow = wave * 16 + (lane >> 2);
    const signed char* gA0 = A + (size_t)(rowBase + srow) * K_DIM + sc * 16;
    const signed char* gA1 = gA0 + (size_t)128 * K_DIM;
    const signed char* gB0 = B + (size_t)(colBase + srow) * K_DIM + sc * 16;
    const signed char* gB1 = gB0 + (size_t)128 * K_DIM;
    const int ldsR0 = wave * 1024;
    const int ldsR1 = 8192 + wave * 1024;

    // ---- fragment read offsets (row=lane&31, chunk=hi+2*kstep, XORed) ----
    const int fsw = ((r5 >> 1) & 3) ^ (((r5 >> 4) & 1) << 1);
    const int ckE = ((hi + 0) ^ fsw) * 16;    // k-step 0: logical chunks {0,1}
    const int ckO = ((hi + 2) ^ fsw) * 16;    // k-step 1: logical chunks {2,3}
    const int aOff = (wm * 128 + r5) * 64;    // + mt*2048
    const int bOff = (wn * 64 + r5) * 64;     // + nt*2048

    intx16 acc[4][2] = {};

    // ---- prologue: stage tiles 0,1 (8 glds/wave) ----
#pragma unroll
    for (int s = 0; s < 2; ++s) {
        const size_t kg = (size_t)s * 64;
        gld_lds16(gA0 + kg, &sA[s][ldsR0]);
        gld_lds16(gA1 + kg, &sA[s][ldsR1]);
        gld_lds16(gB0 + kg, &sB[s][ldsR0]);
        gld_lds16(gB1 + kg, &sB[s][ldsR1]);
    }
    asm volatile("s_waitcnt vmcnt(4)" ::: "memory");  // tile 0 landed
    __builtin_amdgcn_s_barrier();

    int sr = 0;          // read slot   (t % 3)
    int sw = 2;          // stage slot  ((t+2) % 3)
    for (int t = 0; t < 64; ++t) {
        const signed char* sAb = sA[sr];
        const signed char* sBb = sB[sr];

        // ---- k-step 0 reads FIRST (cluster A waits only on these 6) ----
        intx4 fa[4], fb[2];
#pragma unroll
        for (int mt = 0; mt < 4; ++mt)
            fa[mt] = *(const intx4*)(sAb + aOff + mt * 2048 + ckE);
#pragma unroll
        for (int nt = 0; nt < 2; ++nt)
            fb[nt] = *(const intx4*)(sBb + bOff + nt * 2048 + ckE);
        __builtin_amdgcn_sched_barrier(0);

        // ---- k-step 1 reads + stage tile t+2: drain UNDER cluster A ----
        intx4 oa[4], ob[2];
#pragma unroll
        for (int mt = 0; mt < 4; ++mt)
            oa[mt] = *(const intx4*)(sAb + aOff + mt * 2048 + ckO);
#pragma unroll
        for (int nt = 0; nt < 2; ++nt)
            ob[nt] = *(const intx4*)(sBb + bOff + nt * 2048 + ckO);
        if (t <= 61) {
            const size_t kg = (size_t)(t + 2) * 64;
            gld_lds16(gA0 + kg, &sA[sw][ldsR0]);
            gld_lds16(gA1 + kg, &sA[sw][ldsR1]);
            gld_lds16(gB0 + kg, &sB[sw][ldsR0]);
            gld_lds16(gB1 + kg, &sB[sw][ldsR1]);
        }
        __builtin_amdgcn_sched_barrier(0);

        // ---- cluster A: 8 MFMA k-step 0 (compiler emits lgkmcnt(6)) ----
        __builtin_amdgcn_s_setprio(1);
#pragma unroll
        for (int mt = 0; mt < 4; ++mt)
#pragma unroll
            for (int nt = 0; nt < 2; ++nt)
                acc[mt][nt] = __builtin_amdgcn_mfma_i32_32x32x32_i8(
                    fa[mt], fb[nt], acc[mt][nt], 0, 0, 0);
        __builtin_amdgcn_s_setprio(0);
        __builtin_amdgcn_sched_barrier(0);

        // ---- cluster B: 8 MFMA k-step 1 (lgkm already drained) ----
        __builtin_amdgcn_s_setprio(1);
#pragma unroll
        for (int mt = 0; mt < 4; ++mt)
#pragma unroll
            for (int nt = 0; nt < 2; ++nt)
                acc[mt][nt] = __builtin_amdgcn_mfma_i32_32x32x32_i8(
                    oa[mt], ob[nt], acc[mt][nt], 0, 0, 0);
        __builtin_amdgcn_s_setprio(0);
        __builtin_amdgcn_sched_barrier(0);

        // ---- tile boundary: counted vmcnt (t+1 resident), ONE barrier ----
        if (t <= 61)      asm volatile("s_waitcnt vmcnt(4)" ::: "memory");
        else if (t == 62) asm volatile("s_waitcnt vmcnt(0)" ::: "memory");
        __builtin_amdgcn_s_barrier();

        sr = (sr == 2) ? 0 : sr + 1;
        sw = (sw == 2) ? 0 : sw + 1;
    }

    // ---- epilogue: 32x32 C/D layout col=lane&31, row=(reg&3)+8*(reg>>2)+4*hi
    const float s = scale[0];
#pragma unroll
    for (int nt = 0; nt < 2; ++nt) {
        const int gcol = colBase + wn * 64 + nt * 32 + r5;
        const float bv = bias[gcol];
#pragma unroll
        for (int mt = 0; mt < 4; ++mt) {
#pragma unroll
            for (int q = 0; q < 4; ++q) {
                const int row0 = rowBase + wm * 128 + mt * 32 + q * 8 + hi * 4;
                const float4 rs4 = *(const float4*)(row_scale + row0);
                const float rs[4] = {rs4.x, rs4.y, rs4.z, rs4.w};
#pragma unroll
                for (int r = 0; r < 4; ++r)
                    __builtin_nontemporal_store(
                        s * ((float)acc[mt][nt][q * 4 + r] * rs[r] + bv),
                        out + (size_t)(row0 + r) * N_DIM + gcol);
            }
        }
    }
}

// slow but correct fp32 fallback (only if workspace is too small)
__global__ void fallback_kernel(const float* __restrict__ x,
                                const float* __restrict__ w,
                                const float* __restrict__ bias,
                                const float* __restrict__ scale,
                                float* __restrict__ out) {
    int col = blockIdx.x * 64 + (threadIdx.x & 63);
    int row = blockIdx.y * 4 + (threadIdx.x >> 6);
    const float* xr = x + (size_t)row * K_DIM;
    const float* wr = w + (size_t)col * K_DIM;
    float acc = 0.f;
    for (int k = 0; k < K_DIM; k += 4) {
        float4 a = *(const float4*)(xr + k);
        float4 b = *(const float4*)(wr + k);
        acc += a.x * (b.x > 0.f ? 1.f : (b.x < 0.f ? -1.f : 0.f));
        acc += a.y * (b.y > 0.f ? 1.f : (b.y < 0.f ? -1.f : 0.f));
        acc += a.z * (b.z > 0.f ? 1.f : (b.z < 0.f ? -1.f : 0.f));
        acc += a.w * (b.w > 0.f ? 1.f : (b.w < 0.f ? -1.f : 0.f));
    }
    out[(size_t)row * N_DIM + col] = scale[0] * (acc + bias[col]);
}

extern "C" void kernel_launch(void* const* d_in, const int* in_sizes, int n_in,
                              void* d_out, int out_size, void* d_ws, size_t ws_size,
                              hipStream_t stream) {
    const float* x     = (const float*)d_in[0];
    const float* w     = (const float*)d_in[1];
    const float* bias  = (const float*)d_in[2];
    const float* scale = (const float*)d_in[3];
    float* out = (float*)d_out;

    const size_t xb_bytes = (size_t)M_DIM * K_DIM;          // 32 MiB
    const size_t wb_bytes = (size_t)N_DIM * K_DIM;          // 16 MiB
    const size_t need = xb_bytes + wb_bytes + M_DIM * sizeof(float);

    if (ws_size >= need) {
        signed char* xb = (signed char*)d_ws;
        signed char* wb = xb + xb_bytes;
        float* row_scale = (float*)(wb + wb_bytes);
        const unsigned w_blocks = (unsigned)((size_t)N_DIM * K_DIM / 8 / 256); // 8192
        cvt_fused_i8_kernel<<<dim3(M_DIM + w_blocks), 256, 0, stream>>>(
            x, w, xb, wb, row_scale);
        gemm_i8_kernel<<<dim3((M_DIM / 256) * (N_DIM / 256)), 512, 0, stream>>>(
            xb, wb, bias, scale, row_scale, out);
    } else {
        dim3 grid(N_DIM / 64, M_DIM / 4);
        fallback_kernel<<<grid, 256, 0, stream>>>(x, w, bias, scale, out);
    }
}